// Round 15
// baseline (276.783 us; speedup 1.0000x reference)
//
#include <hip/hip_runtime.h>
#include <cstddef>

#define D_MODEL 1024
#define NH 16
#define HD 64
#define BATCH 4
#define SEQ 2048
#define MTOT (BATCH * SEQ)  // 8192

typedef _Float16 half8 __attribute__((ext_vector_type(8)));
typedef _Float16 half4v __attribute__((ext_vector_type(4)));
typedef float f32x4 __attribute__((ext_vector_type(4)));

#if __has_builtin(__builtin_amdgcn_exp2f)
#define EXP2(x) __builtin_amdgcn_exp2f(x)
#else
#define EXP2(x) __expf((x)*0.69314718056f)
#endif

// async global->LDS, 16B per lane. LDS dest must be wave-uniform base (+lane*16 implicit).
#define ASYNC_COPY16(g, l)                                                    \
    __builtin_amdgcn_global_load_lds(                                         \
        (__attribute__((address_space(1))) const void*)(g),                   \
        (__attribute__((address_space(3))) void*)(l), 16, 0, 0)

// Swizzled LDS access: logical element (R, CH f16-cols) of a [*][64] f16 tile
// lives at byte R*128 + ((CH*2) ^ ((R&7)<<4)).  Producer (glds with inverse-swz
// global source, or ds_write at the swizzled offset) pairs with this read:
// conflict-free (proven 0-conflict in the GEMM).
#define LDSFRAG(S, R, CH)                                                     \
    (*(const half8*)((const char*)(S) + ((R) << 7) +                          \
                     ((((CH) << 1)) ^ (((R) & 7) << 4))))
// matching swizzled-write address (byte pointer) for row R, f16-col CH
#define LDSWADDR(S, R, CH)                                                    \
    ((half8*)((char*)(S) + ((R) << 7) + ((((CH) << 1)) ^ (((R) & 7) << 4))))

// ---------------------------------------------------------------------------
// prep (round-15: weights only — x fp32->f16 conversion fused into the QKV
// GEMM's A-staging, deleting the 64 MB x round-trip and a serialized kernel
// dependency).  1024 blocks: 4 weight matrices fp32 [k][n] -> f16 [n][k].
// ---------------------------------------------------------------------------
__global__ __launch_bounds__(256) void prep(
    const float* __restrict__ W0, const float* __restrict__ W1,
    const float* __restrict__ W2, const float* __restrict__ W3,
    _Float16* __restrict__ T0, _Float16* __restrict__ T1,
    _Float16* __restrict__ T2, _Float16* __restrict__ T3)
{
    __shared__ float T[64][65];
    const int t = blockIdx.x;
    const int mtx = t >> 8;
    const float* W = (mtx == 0) ? W0 : (mtx == 1) ? W1 : (mtx == 2) ? W2 : W3;
    _Float16*   Wt = (mtx == 0) ? T0 : (mtx == 1) ? T1 : (mtx == 2) ? T2 : T3;
    const int tile = t & 255;
    const int k0 = (tile >> 4) * 64, n0 = (tile & 15) * 64;
    const int r = threadIdx.x >> 4, c4 = (threadIdx.x & 15) * 4;

#pragma unroll
    for (int i = 0; i < 4; ++i) {
        float4 v = *(const float4*)(W + (size_t)(k0 + r + 16 * i) * 1024 + n0 + c4);
        T[r + 16 * i][c4 + 0] = v.x; T[r + 16 * i][c4 + 1] = v.y;
        T[r + 16 * i][c4 + 2] = v.z; T[r + 16 * i][c4 + 3] = v.w;
    }
    __syncthreads();
#pragma unroll
    for (int i = 0; i < 4; ++i) {
        const int n = r + 16 * i;
        half4v h;
        h[0] = (_Float16)T[c4 + 0][n]; h[1] = (_Float16)T[c4 + 1][n];
        h[2] = (_Float16)T[c4 + 2][n]; h[3] = (_Float16)T[c4 + 3][n];
        *(half4v*)(Wt + (size_t)(n0 + n) * 1024 + k0 + c4) = h;
    }
}

// ---------------------------------------------------------------------------
// MFMA f16 GEMM — round-1 structure (1-phase, single-buffer; rounds 3/4/12
// falsified deeper pipelines at this shape).  Round-15 change: for QKV=1 the
// A operand is RAW FP32 x — staged via register-load fp32 -> cvt f16 ->
// swizzled ds_write_b128 (the attn-v11-proven producer for LDSFRAG), fusing
// the former prep x-conversion.  B stays glds with inverse-swz source.
// QKV=0 (out-proj) keeps f16 glds for both operands.  Q pre-scale
// (0.125*log2e) folded into the z==0 epilogue.  setprio not applied (m190).
// ---------------------------------------------------------------------------
template <int QKV>
__global__ __launch_bounds__(256) void gemm_mfma(
    const void* __restrict__ Ap,
    const _Float16* __restrict__ Bt0, const _Float16* __restrict__ Bt1, const _Float16* __restrict__ Bt2,
    const float* __restrict__ bi0, const float* __restrict__ bi1, const float* __restrict__ bi2,
    void* __restrict__ C0, void* __restrict__ C1, void* __restrict__ C2)
{
    const int L = blockIdx.x;
    const int y = L & 63;
    const int c_ = L >> 6;
    const int z  = QKV ? (c_ >> 3) : 0;
    const int xb = QKV ? (c_ & 7) : c_;

    const _Float16* Bt = (z == 0) ? Bt0 : (z == 1) ? Bt1 : Bt2;
    const float*   bia = (z == 0) ? bi0 : (z == 1) ? bi1 : bi2;
    void*            C = (z == 0) ? C0  : (z == 1) ? C1  : C2;

    __shared__ _Float16 As[128][64];
    __shared__ _Float16 Bs[128][64];

    const int tid  = threadIdx.x;
    const int w    = tid >> 6;
    const int lane = tid & 63;
    const int l15  = lane & 15;
    const int lg   = lane >> 4;
    const int m0 = y * 128;
    const int n0 = xb * 128;
    const int wm = (w >> 1) * 64, wn = (w & 1) * 64;

    const int rsub = lane >> 3;                       // 0..7
    const int cswz = ((lane & 7) ^ rsub) * 8;         // halves (glds inverse swizzle)

    const int srow  = tid >> 3;                       // 0..31 (reg-staging rows)
    const int scol8 = (tid & 7) * 8;                  // 8-col chunk

    // B: glds source (swizzled); A: fp32 source (QKV) or f16 glds (out-proj)
    const _Float16* gB = Bt + (size_t)(n0 + 32 * w + rsub) * 1024 + cswz;
    char* lB = (char*)Bs + (size_t)(w * 4) * 1024;

    const float*    gx = (const float*)Ap + (size_t)(m0 + srow) * 1024 + scol8;   // QKV=1
    const _Float16* gA = (const _Float16*)Ap + (size_t)(m0 + 32 * w + rsub) * 1024 + cswz; // QKV=0
    char* lA = (char*)As + (size_t)(w * 4) * 1024;

    f32x4 acc[4][4];
#pragma unroll
    for (int i = 0; i < 4; ++i)
#pragma unroll
        for (int j = 0; j < 4; ++j) { acc[i][j][0] = 0.f; acc[i][j][1] = 0.f; acc[i][j][2] = 0.f; acc[i][j][3] = 0.f; }

    // A-register prefetch for tile 0 (QKV path)
    float4 axr[4][2];
    if constexpr (QKV) {
#pragma unroll
        for (int j = 0; j < 4; ++j) {
            axr[j][0] = *(const float4*)(gx + (size_t)(32 * j) * 1024);
            axr[j][1] = *(const float4*)(gx + (size_t)(32 * j) * 1024 + 4);
        }
    }

    for (int kt = 0; kt < 16; ++kt) {
        const int k0 = kt * 64;
        __syncthreads();  // WAR: all reads of previous tile done before overwrite

        if constexpr (QKV) {
            // A: convert prefetched fp32 regs -> f16, swizzled ds_write_b128
#pragma unroll
            for (int j = 0; j < 4; ++j) {
                half8 h;
                h[0] = (_Float16)axr[j][0].x; h[1] = (_Float16)axr[j][0].y;
                h[2] = (_Float16)axr[j][0].z; h[3] = (_Float16)axr[j][0].w;
                h[4] = (_Float16)axr[j][1].x; h[5] = (_Float16)axr[j][1].y;
                h[6] = (_Float16)axr[j][1].z; h[7] = (_Float16)axr[j][1].w;
                *LDSWADDR(As, srow + 32 * j, scol8) = h;
            }
        } else {
#pragma unroll
            for (int i = 0; i < 4; ++i)
                ASYNC_COPY16(gA + (size_t)(8 * i) * 1024 + k0, lA + i * 1024);
        }
#pragma unroll
        for (int i = 0; i < 4; ++i)
            ASYNC_COPY16(gB + (size_t)(8 * i) * 1024 + k0, lB + i * 1024);

        __syncthreads();  // drains lgkm (A ds_writes) + vmcnt (B glds) -> tile visible

        if constexpr (QKV) {
            // prefetch next tile's fp32 A into registers (fly during compute)
            if (kt < 15) {
                const int k0n = k0 + 64;
#pragma unroll
                for (int j = 0; j < 4; ++j) {
                    axr[j][0] = *(const float4*)(gx + (size_t)(32 * j) * 1024 + k0n);
                    axr[j][1] = *(const float4*)(gx + (size_t)(32 * j) * 1024 + k0n + 4);
                }
            }
        }

#pragma unroll
        for (int c = 0; c < 2; ++c) {
            half8 af[4], bf[4];
#pragma unroll
            for (int i = 0; i < 4; ++i) af[i] = LDSFRAG(As, wm + 16 * i + l15, 32 * c + 8 * lg);
#pragma unroll
            for (int j = 0; j < 4; ++j) bf[j] = LDSFRAG(Bs, wn + 16 * j + l15, 32 * c + 8 * lg);
#pragma unroll
            for (int i = 0; i < 4; ++i)
#pragma unroll
                for (int j = 0; j < 4; ++j)
                    acc[i][j] = __builtin_amdgcn_mfma_f32_16x16x32_f16(af[i], bf[j], acc[i][j], 0, 0, 0);
        }
    }

    float bvv[4];
#pragma unroll
    for (int j = 0; j < 4; ++j) bvv[j] = bia[n0 + wn + 16 * j + l15];

#pragma unroll
    for (int i = 0; i < 4; ++i)
#pragma unroll
        for (int j = 0; j < 4; ++j)
#pragma unroll
            for (int r = 0; r < 4; ++r) {
                const int m = m0 + wm + 16 * i + 4 * lg + r;
                const int n = n0 + wn + 16 * j + l15;
                float val = acc[i][j][r] + bvv[j];
                if (QKV) {
                    if (z == 0) val *= 0.18033688f;   // fold Q pre-scale (0.125*log2e)
                    const int bb = m >> 11, ss = m & 2047, hh = n >> 6, hd = n & 63;
                    if (z < 2)   // Q, K: [bh][s][hd]
                        ((_Float16*)C)[((size_t)(bb * NH + hh) * SEQ + ss) * HD + hd] = (_Float16)val;
                    else         // V: transposed [bh][d][s]
                        ((_Float16*)C)[((size_t)(bb * NH + hh) * HD + hd) * SEQ + ss] = (_Float16)val;
                } else {
                    ((float*)C)[(size_t)m * 1024 + n] = val;
                }
            }
}

// ---------------------------------------------------------------------------
// Causal flash attention v12 (round-14 winner, unchanged): double-buffered
// Ks/Vs, ONE barrier/tile, dual Q-fragment, swapped QK^T packed-half4 Ps,
// XOR-swizzled K/V, T5 setprio around MFMA clusters (+5us, m191-consistent),
// 1024 blocks longest-first, bh->XCD affinity.  Q arrives pre-scaled.
// ---------------------------------------------------------------------------
__global__ __launch_bounds__(256, 3) void attn_fwd_mfma(
    const _Float16* __restrict__ Q, const _Float16* __restrict__ K,
    const _Float16* __restrict__ Vt, _Float16* __restrict__ O)
{
    __shared__ _Float16 Ks[2][64][64];
    __shared__ _Float16 Vs[2][64][64];
    __shared__ _Float16 Ps[8][16][72];   // [q-group 2w+u][q=l15][k], pitch 144B

    const int tid  = threadIdx.x;
    const int w    = tid >> 6;
    const int lane = tid & 63;
    const int l15  = lane & 15;
    const int lg   = lane >> 4;

    const int bid = blockIdx.x;
    const int bh  = bid & 63;          // bid%8 == bh%8 -> XCD affinity
    const int qt  = 15 - (bid >> 6);   // longest blocks dispatch first
    const int b  = bh >> 4, h = bh & 15;

    const _Float16* Qb  = Q  + (size_t)bh * SEQ * HD;
    const _Float16* Kb  = K  + (size_t)bh * SEQ * HD;   // [s][d]
    const _Float16* Vtb = Vt + (size_t)bh * HD * SEQ;   // [d][s]

    const int srow = tid >> 3;         // 0..31
    const int scol = (tid & 7) * 8;    // f16 cols

    const int q0 = qt * 128;
    const int ntiles = 2 * qt + 2;

    // ---- Q: two fragments per wave (pre-scaled by the QKV GEMM) ----
    half8 qa[2][2];
#pragma unroll
    for (int u = 0; u < 2; ++u) {
        const _Float16* qp = Qb + (size_t)(q0 + 16 * (2 * w + u) + l15) * HD + 8 * lg;
        qa[u][0] = *(const half8*)(qp);
        qa[u][1] = *(const half8*)(qp + 32);
    }

    f32x4 o_[2][4];
#pragma unroll
    for (int u = 0; u < 2; ++u)
#pragma unroll
        for (int ft = 0; ft < 4; ++ft) { o_[u][ft][0] = 0.f; o_[u][ft][1] = 0.f; o_[u][ft][2] = 0.f; o_[u][ft][3] = 0.f; }
    float lp_t[2] = {0.f, 0.f};

    half8 kreg[2], vreg[2];
#pragma unroll
    for (int j = 0; j < 2; ++j) {
        kreg[j] = *(const half8*)(Kb  + (size_t)(srow + 32 * j) * HD + scol);
        vreg[j] = *(const half8*)(Vtb + (size_t)(srow + 32 * j) * SEQ + scol);
    }

    for (int kt = 0; kt < ntiles; ++kt) {
        const int cur = kt & 1;
        // ---- stage K/V(kt) into buf[cur] (WAR vs kt-2 reads: separated by
        //      sync(kt-1)); then the single barrier makes it visible ----
#pragma unroll
        for (int j = 0; j < 2; ++j) {
            const int row = srow + 32 * j;
            *LDSWADDR(&Ks[cur][0][0], row, scol) = kreg[j];
            *LDSWADDR(&Vs[cur][0][0], row, scol) = vreg[j];
        }
        __syncthreads();

        // prefetch tile kt+1 into registers (in flight during compute)
        if (kt + 1 < ntiles) {
            const int k0 = (kt + 1) * 64;
#pragma unroll
            for (int j = 0; j < 2; ++j) {
                kreg[j] = *(const half8*)(Kb  + (size_t)(k0 + srow + 32 * j) * HD + scol);
                vreg[j] = *(const half8*)(Vtb + (size_t)(srow + 32 * j) * SEQ + k0 + scol);
            }
        }

        // ---- S^T = K Q^T : 16 MFMAs on 8 kb reads (2 q-frags share kb) ----
        f32x4 s0[4], s1[4];
#pragma unroll
        for (int f = 0; f < 4; ++f) {
            s0[f][0] = 0.f; s0[f][1] = 0.f; s0[f][2] = 0.f; s0[f][3] = 0.f;
            s1[f][0] = 0.f; s1[f][1] = 0.f; s1[f][2] = 0.f; s1[f][3] = 0.f;
        }
        __builtin_amdgcn_s_setprio(1);
#pragma unroll
        for (int c = 0; c < 2; ++c)
#pragma unroll
            for (int f = 0; f < 4; ++f) {
                half8 kb = LDSFRAG(&Ks[cur][0][0], 16 * f + l15, 32 * c + 8 * lg);
                s0[f] = __builtin_amdgcn_mfma_f32_16x16x32_f16(kb, qa[0][c], s0[f], 0, 0, 0);
                s1[f] = __builtin_amdgcn_mfma_f32_16x16x32_f16(kb, qa[1][c], s1[f], 0, 0, 0);
            }
        __builtin_amdgcn_s_setprio(0);

        // ---- p = exp2(s), mask (diag spans last 2 tiles), packed stash ----
        const bool dg = (kt >= 2 * qt);
#pragma unroll
        for (int u = 0; u < 2; ++u) {
            const int qg = q0 + 16 * (2 * w + u) + l15;   // global q row
#pragma unroll
            for (int f = 0; f < 4; ++f) {
                half4v ph;
#pragma unroll
                for (int r = 0; r < 4; ++r) {
                    const float sv = (u == 0) ? s0[f][r] : s1[f][r];
                    float p = EXP2(sv);
                    if (dg && (kt * 64 + 16 * f + 4 * lg + r > qg)) p = 0.f;
                    lp_t[u] += p;
                    ph[r] = (_Float16)p;
                }
                *(half4v*)&Ps[2 * w + u][l15][16 * f + 4 * lg] = ph;
            }
        }

        // ---- O += P V : 16 MFMAs on 8 vb reads ----
        half8 pa0[2], pa1[2];
        pa0[0] = *(const half8*)&Ps[2 * w][l15][8 * lg];
        pa0[1] = *(const half8*)&Ps[2 * w][l15][32 + 8 * lg];
        pa1[0] = *(const half8*)&Ps[2 * w + 1][l15][8 * lg];
        pa1[1] = *(const half8*)&Ps[2 * w + 1][l15][32 + 8 * lg];
        __builtin_amdgcn_s_setprio(1);
#pragma unroll
        for (int c = 0; c < 2; ++c)
#pragma unroll
            for (int ft = 0; ft < 4; ++ft) {
                half8 vb = LDSFRAG(&Vs[cur][0][0], 16 * ft + l15, 32 * c + 8 * lg);
                o_[0][ft] = __builtin_amdgcn_mfma_f32_16x16x32_f16(pa0[c], vb, o_[0][ft], 0, 0, 0);
                o_[1][ft] = __builtin_amdgcn_mfma_f32_16x16x32_f16(pa1[c], vb, o_[1][ft], 0, 0, 0);
            }
        __builtin_amdgcn_s_setprio(0);
    }

    // ---- epilogue per fragment: rowsum at q=l15; O rows q=4lg+r ----
#pragma unroll
    for (int u = 0; u < 2; ++u) {
        float rs = lp_t[u];
        rs += __shfl_xor(rs, 16);
        rs += __shfl_xor(rs, 32);
        // lanes 0..15 now hold rowsum(q = lane index) for this fragment
#pragma unroll
        for (int r = 0; r < 4; ++r) {
            const float inv = 1.0f / __shfl(rs, 4 * lg + r, 64);
            _Float16* orow = O + (size_t)(b * SEQ + q0 + 16 * (2 * w + u) + 4 * lg + r) * D_MODEL + h * HD + l15;
#pragma unroll
            for (int ft = 0; ft < 4; ++ft) orow[16 * ft] = (_Float16)(o_[u][ft][r] * inv);
        }
    }
}

// ---------------------------------------------------------------------------
extern "C" void kernel_launch(void* const* d_in, const int* in_sizes, int n_in,
                              void* d_out, int out_size, void* d_ws, size_t ws_size,
                              hipStream_t stream)
{
    const float* x  = (const float*)d_in[0];
    const float* wq = (const float*)d_in[1];
    const float* bq = (const float*)d_in[2];
    const float* wk = (const float*)d_in[3];
    const float* bk = (const float*)d_in[4];
    const float* wv = (const float*)d_in[5];
    const float* bv = (const float*)d_in[6];
    const float* wo = (const float*)d_in[7];
    const float* bo = (const float*)d_in[8];
    float* out = (float*)d_out;

    const size_t SZ = (size_t)MTOT * D_MODEL;  // 8388608
    const size_t WZ = (size_t)D_MODEL * D_MODEL;

    _Float16* wtq = (_Float16*)d_ws;
    _Float16* wtk = wtq + WZ;
    _Float16* wtv = wtk + WZ;
    _Float16* wto = wtv + WZ;
    _Float16* Qh  = wto + WZ;
    _Float16* Kh  = Qh + SZ;
    _Float16* Vtg = Kh + SZ;   // V, already transposed [bh][d][s]
    _Float16* AOh = Vtg + SZ;  // total ~72 MiB (xh eliminated)

    // prep: weights only (x conversion fused into QKV A-staging)
    prep<<<dim3(1024), 256, 0, stream>>>(wq, wk, wv, wo, wtq, wtk, wtv, wto);
    // QKV projection: XCD-affinity 1D grid (1536 blocks); A = raw fp32 x
    gemm_mfma<1><<<dim3(1536), 256, 0, stream>>>(x, wtq, wtk, wtv, bq, bk, bv, Qh, Kh, Vtg);
    // attention: 1024 blocks (16 qt x 64 bh), longest-first, bh-XCD affinity
    attn_fwd_mfma<<<dim3(1024), 256, 0, stream>>>(Qh, Kh, Vtg, AOh);
    // output projection: XCD-affinity 1D grid (512 blocks), f16 glds A
    gemm_mfma<0><<<dim3(512), 256, 0, stream>>>(AOh, wto, wto, wto, bo, bo, bo, out, out, out);
}